// Round 1
// baseline (951.102 us; speedup 1.0000x reference)
//
#include <hip/hip_runtime.h>
#include <math.h>

#define TPB 512
#define TILE_B 32
#define TSTEPS 28
#define IDIM 28
#define HDIM 128
#define KDIM 156          // H + I combined k-dim
#define GDIM 512          // 4H gates
#define KC 8              // k-chunk staged per double-buffer slot
#define NCHUNK 20         // 19 chunks of 8 + 1 chunk of 4 = 156
#define CDIM 10
#define VROW 39           // KDIM/4 float4 per vbuf row

// Pack W_cat = [W_hh | W_ih] into k-major, unit/type-interleaved layout:
// P[k][u][t] = W_cat[t*128+u][k],  k in [0,156), u in [0,128), t in [0,4)
__global__ __launch_bounds__(256) void pack_w_kernel(const float* __restrict__ Wih,
                                                     const float* __restrict__ Whh,
                                                     float* __restrict__ P) {
    int e = blockIdx.x * 256 + threadIdx.x;
    if (e >= KDIM * GDIM) return;
    int k  = e >> 9;          // 0..155
    int gp = e & 511;         // u*4 + t
    int u  = gp >> 2, t = gp & 3;
    int g  = t * HDIM + u;    // PyTorch gate order i,f,g,o
    P[e] = (k < HDIM) ? Whh[g * HDIM + k] : Wih[g * IDIM + (k - HDIM)];
}

__global__ __launch_bounds__(TPB, 2) void lstm_kernel(
    const float* __restrict__ x,      // [B][T][I]
    const float* __restrict__ P,      // [156][128][4] packed weights
    const float* __restrict__ b_ih, const float* __restrict__ b_hh,
    const float* __restrict__ Wfc,    // [10][128]
    const float* __restrict__ b_fc,   // [10]
    float* __restrict__ out)          // [B][10]
{
    __shared__ float vbuf[TILE_B * KDIM];     // rows x [h(128) | x_t(28)]  (19968 B)
    __shared__ float wbuf[2 * KC * GDIM];     // double-buffered W chunks   (32768 B)

    const int tid = threadIdx.x;
    const int u   = tid & 127;                // unit 0..127 (wave-contiguous)
    const int rq  = tid >> 7;                 // row quad 0..3 (wave-uniform)
    const int r0  = rq * 8;
    const int b0  = blockIdx.x * TILE_B;

    // bias for this thread's 4 gates (i,f,g,o) of unit u
    float4 bias;
    bias.x = b_ih[0 * HDIM + u] + b_hh[0 * HDIM + u];
    bias.y = b_ih[1 * HDIM + u] + b_hh[1 * HDIM + u];
    bias.z = b_ih[2 * HDIM + u] + b_hh[2 * HDIM + u];
    bias.w = b_ih[3 * HDIM + u] + b_hh[3 * HDIM + u];

    // zero h region of vbuf (rows are 156 floats; h = first 32 float4 of each row)
    {
        float4 z = {0.f, 0.f, 0.f, 0.f};
        float4* vb4 = (float4*)vbuf;
        #pragma unroll
        for (int q = 0; q < 2; ++q) {
            int f = tid + q * TPB;            // 0..1023 over (row, j)
            int r = f >> 5, j = f & 31;
            vb4[r * VROW + j] = z;
        }
    }
    // stage x_0 into vbuf[r][128..155]
    if (tid < 224) {
        int r = tid / 7, q = tid % 7;
        const float4* xs = (const float4*)(x + (size_t)(b0 + r) * (TSTEPS * IDIM));
        float4 xv = xs[q];                    // t=0: offset 7*t + q
        *((float4*)(vbuf + r * KDIM + HDIM) + q) = xv;
    }

    float cst[8];
    #pragma unroll
    for (int r = 0; r < 8; ++r) cst[r] = 0.f;

    // preload chunk 0 into registers
    const float4* P4 = (const float4*)P;
    float4 wreg[2];
    wreg[0] = P4[tid];
    wreg[1] = P4[TPB + tid];

    float4* wb4all = (float4*)wbuf;

    for (int t = 0; t < TSTEPS; ++t) {
        float4 acc[8];
        #pragma unroll
        for (int r = 0; r < 8; ++r) acc[r] = bias;

        for (int ci = 0; ci < NCHUNK; ++ci) {
            const int len = (ci < NCHUNK - 1) ? KC : 4;
            const int nf4 = len * (GDIM / 4);                 // 1024 or 512
            float4* wb4 = wb4all + (ci & 1) * (KC * GDIM / 4);
            // commit staged regs to LDS (implicit vmcnt wait)
            wb4[tid] = wreg[0];
            if (nf4 > TPB) wb4[TPB + tid] = wreg[1];
            __syncthreads();
            // issue async loads for next chunk (wraps to chunk 0 for next step)
            {
                int cn = ci + 1; if (cn == NCHUNK) cn = 0;
                int base = cn * KC * (GDIM / 4);
                int nlen = (cn < NCHUNK - 1) ? KC : 4;
                wreg[0] = P4[base + tid];
                if (nlen * (GDIM / 4) > TPB) wreg[1] = P4[base + TPB + tid];
            }
            // compute this chunk: acc[r][t] += v[r][k] * W[k][u][t]
            const int k0 = ci * KC;
            const float4* vb4 = (const float4*)vbuf;
            #pragma unroll
            for (int kk = 0; kk < KC; kk += 4) {
                if (kk < len) {
                    float4 w0 = wb4[(kk + 0) * 128 + u];
                    float4 w1 = wb4[(kk + 1) * 128 + u];
                    float4 w2 = wb4[(kk + 2) * 128 + u];
                    float4 w3 = wb4[(kk + 3) * 128 + u];
                    int kv = (k0 + kk) >> 2;
                    #pragma unroll
                    for (int r = 0; r < 8; ++r) {
                        float4 v = vb4[(r0 + r) * VROW + kv];
                        float4 a = acc[r];
                        a.x += v.x * w0.x; a.y += v.x * w0.y; a.z += v.x * w0.z; a.w += v.x * w0.w;
                        a.x += v.y * w1.x; a.y += v.y * w1.y; a.z += v.y * w1.z; a.w += v.y * w1.w;
                        a.x += v.z * w2.x; a.y += v.z * w2.y; a.z += v.z * w2.z; a.w += v.z * w2.w;
                        a.x += v.w * w3.x; a.y += v.w * w3.y; a.z += v.w * w3.z; a.w += v.w * w3.w;
                        acc[r] = a;
                    }
                }
            }
        }
        __syncthreads();   // all gate compute done before vbuf is mutated

        // activations + c/h update (c lives in registers), write new h
        #pragma unroll
        for (int r = 0; r < 8; ++r) {
            float ig = 1.f / (1.f + __expf(-acc[r].x));
            float fg = 1.f / (1.f + __expf(-acc[r].y));
            float gg = 1.f - 2.f / (__expf(2.f * acc[r].z) + 1.f);   // tanh
            float og = 1.f / (1.f + __expf(-acc[r].w));
            float c  = fg * cst[r] + ig * gg;
            cst[r] = c;
            float h  = og * (1.f - 2.f / (__expf(2.f * c) + 1.f));
            vbuf[(r0 + r) * KDIM + u] = h;
        }
        // stage x_{t+1}
        if (t + 1 < TSTEPS && tid < 224) {
            int r = tid / 7, q = tid % 7;
            const float4* xs = (const float4*)(x + (size_t)(b0 + r) * (TSTEPS * IDIM));
            float4 xv = xs[(t + 1) * 7 + q];
            *((float4*)(vbuf + r * KDIM + HDIM) + q) = xv;
        }
        // visibility handled by the barrier inside next step's first chunk
    }

    __syncthreads();   // final h visible to all

    // FC + ReLU: out[b][c] = relu(dot(h[b], Wfc[c]) + b_fc[c])
    if (tid < TILE_B * CDIM) {
        int r = tid / CDIM, c = tid - (tid / CDIM) * CDIM;
        const float4* vb4 = (const float4*)vbuf + r * VROW;
        const float4* wf4 = (const float4*)(Wfc + c * HDIM);
        float s = b_fc[c];
        #pragma unroll
        for (int j = 0; j < 32; ++j) {
            float4 v = vb4[j];
            float4 w = wf4[j];
            s += v.x * w.x + v.y * w.y + v.z * w.z + v.w * w.w;
        }
        out[(size_t)(b0 + r) * CDIM + c] = fmaxf(s, 0.f);
    }
}

extern "C" void kernel_launch(void* const* d_in, const int* in_sizes, int n_in,
                              void* d_out, int out_size, void* d_ws, size_t ws_size,
                              hipStream_t stream) {
    const float* x   = (const float*)d_in[0];
    const float* Wih = (const float*)d_in[1];
    const float* Whh = (const float*)d_in[2];
    const float* bih = (const float*)d_in[3];
    const float* bhh = (const float*)d_in[4];
    const float* Wfc = (const float*)d_in[5];
    const float* bfc = (const float*)d_in[6];
    float* out = (float*)d_out;
    float* P   = (float*)d_ws;   // 156*512 floats = 319488 B

    hipLaunchKernelGGL(pack_w_kernel, dim3((KDIM * GDIM + 255) / 256), dim3(256), 0, stream,
                       Wih, Whh, P);
    hipLaunchKernelGGL(lstm_kernel, dim3(8192 / TILE_B), dim3(TPB), 0, stream,
                       x, P, bih, bhh, Wfc, bfc, out);
}

// Round 2
// 148.835 us; speedup vs baseline: 6.3903x; 6.3903x over previous
//
#include <hip/hip_runtime.h>
#include <math.h>

typedef __attribute__((ext_vector_type(8)))  _Float16 half8;
typedef __attribute__((ext_vector_type(4)))  _Float16 half4;
typedef __attribute__((ext_vector_type(16))) float    f32x16;

#define TSTEPS 28
#define IDIM   28
#define HDIM   128
#define NCH    10      // K chunks of 16: 160 = 128 (h) + 28 (x) + 4 (zero pad)
#define TILE_B 32
#define CDIM   10

#if __has_builtin(__builtin_amdgcn_exp2f)
#define EXP2F(x) __builtin_amdgcn_exp2f(x)
#else
#define EXP2F(x) exp2f(x)
#endif
#if __has_builtin(__builtin_amdgcn_rcpf)
#define RCPF(x) __builtin_amdgcn_rcpf(x)
#else
#define RCPF(x) (1.0f / (x))
#endif

// P_packed[kc][ct][lane][j] (f16): B-fragment order for mfma_f32_32x32x16_f16.
// Element = W_cat[k][col], k = 16*kc + 8*(lane>>5) + j, col = 32*ct + (lane&31).
// col -> gate type t = col>>7, unit u = col&127 (PyTorch order i,f,g,o).
__global__ __launch_bounds__(256) void pack_w(const float* __restrict__ Wih,
                                              const float* __restrict__ Whh,
                                              _Float16* __restrict__ P) {
    int e = blockIdx.x * 256 + threadIdx.x;       // 10*16*64*8 = 81920
    if (e >= NCH * 16 * 64 * 8) return;
    int j  = e & 7;
    int ln = (e >> 3) & 63;
    int ct = (e >> 9) & 15;
    int kc = e >> 13;
    int k   = kc * 16 + ((ln >> 5) << 3) + j;
    int col = ct * 32 + (ln & 31);
    int tt = col >> 7, uu = col & 127;
    float v = 0.f;
    if (k < HDIM)              v = Whh[(tt * HDIM + uu) * HDIM + k];
    else if (k < HDIM + IDIM)  v = Wih[(tt * HDIM + uu) * IDIM + (k - HDIM)];
    P[e] = (_Float16)v;
}

__global__ __launch_bounds__(256, 1) void lstm_kernel(
    const float* __restrict__ x,          // [B][28][28] fp32
    const _Float16* __restrict__ P,       // packed weights, 160 KB
    const float* __restrict__ b_ih, const float* __restrict__ b_hh,
    const float* __restrict__ Wfc,        // [10][128]
    const float* __restrict__ b_fc,       // [10]
    float* __restrict__ out)              // [B][10]
{
    // A-fragment buffer: frag[kc][slot][j], slot = sigma(lane') = lane' ^ ((lane'>>4)&2)
    __shared__ __align__(16) _Float16 frag[NCH][64][8];      // 10 KB
    __shared__ __align__(16) float hplain[TILE_B][132];      // 16.9 KB (FC epilogue)

    const int tid = threadIdx.x;
    const int l   = tid & 63;
    const int w   = tid >> 6;                 // wave 0..3
    const int b0  = blockIdx.x * TILE_B;
    const int u   = w * 32 + (l & 31);        // this lane's unit

    // ---- load all B fragments into registers (persist across all 28 steps) ----
    half8 breg[4][NCH];                       // 160 VGPRs
    {
        const half8* Pp = (const half8*)P;
        #pragma unroll
        for (int t4 = 0; t4 < 4; ++t4)
            #pragma unroll
            for (int kc = 0; kc < NCH; ++kc)
                breg[t4][kc] = Pp[(kc * 16 + (t4 * 4 + w)) * 64 + l];
    }
    float biasv[4];
    #pragma unroll
    for (int t4 = 0; t4 < 4; ++t4)
        biasv[t4] = b_ih[t4 * HDIM + u] + b_hh[t4 * HDIM + u];

    // ---- zero h chunks (0..7) and the k=156..159 pad in chunk 9 ----
    {
        float4 z = {0.f, 0.f, 0.f, 0.f};
        ((float4*)frag)[tid]       = z;       // bytes 0..4095
        ((float4*)frag)[tid + 256] = z;       // bytes 4096..8191 (chunks 0..7)
        if (tid < 32) {
            int slot = (32 + tid) ^ (((32 + tid) >> 4) & 2);
            float2 z2 = {0.f, 0.f};
            *((float2*)&frag[9][slot][4]) = z2;
        }
    }
    // ---- stage x_0 into chunks 8,9 ----
    if (tid < 224) {
        int row = tid / 7, xg = tid % 7, xi = xg * 4;
        const float4* xs = (const float4*)(x + ((size_t)(b0 + row) * TSTEPS + 0) * IDIM);
        float4 xv = xs[xg];
        half4 hv = {(_Float16)xv.x, (_Float16)xv.y, (_Float16)xv.z, (_Float16)xv.w};
        int lp = row + 32 * ((xi >> 3) & 1);
        int slot = lp ^ ((lp >> 4) & 2);
        *((half4*)&frag[8 + (xi >> 4)][slot][xi & 7]) = hv;
    }

    float cst[16];
    #pragma unroll
    for (int r = 0; r < 16; ++r) cst[r] = 0.f;

    const int sl = l ^ ((l >> 4) & 2);        // A-read slot (sigma applied)

    __syncthreads();

    for (int t = 0; t < TSTEPS; ++t) {
        f32x16 acc[4];
        #pragma unroll
        for (int t4 = 0; t4 < 4; ++t4)
            #pragma unroll
            for (int r = 0; r < 16; ++r) acc[t4][r] = biasv[t4];

        #pragma unroll
        for (int kc = 0; kc < NCH; ++kc) {
            half8 a = *((const half8*)&frag[kc][sl][0]);
            acc[0] = __builtin_amdgcn_mfma_f32_32x32x16_f16(a, breg[0][kc], acc[0], 0, 0, 0);
            acc[1] = __builtin_amdgcn_mfma_f32_32x32x16_f16(a, breg[1][kc], acc[1], 0, 0, 0);
            acc[2] = __builtin_amdgcn_mfma_f32_32x32x16_f16(a, breg[2][kc], acc[2], 0, 0, 0);
            acc[3] = __builtin_amdgcn_mfma_f32_32x32x16_f16(a, breg[3][kc], acc[3], 0, 0, 0);
        }
        __syncthreads();   // all waves done reading frag before we overwrite h / x

        // activations: lane holds i,f,g,o for unit u, 16 rows
        const int kc_h = u >> 4;
        const int lpb  = 32 * ((l >> 3) & 1);
        const int jh   = l & 7;
        #pragma unroll
        for (int r = 0; r < 16; ++r) {
            float ig = acc[0][r], fg = acc[1][r], gg = acc[2][r], og = acc[3][r];
            float is = RCPF(1.f + EXP2F(ig * -1.44269504f));
            float fs = RCPF(1.f + EXP2F(fg * -1.44269504f));
            float os = RCPF(1.f + EXP2F(og * -1.44269504f));
            float gt = 1.f - 2.f * RCPF(1.f + EXP2F(gg * 2.88539008f));
            float c  = fs * cst[r] + is * gt;
            cst[r] = c;
            float tc = 1.f - 2.f * RCPF(1.f + EXP2F(c * 2.88539008f));
            float h  = os * tc;
            int m  = (r & 3) + 8 * (r >> 2) + 4 * (l >> 5);
            int lp = m + lpb;
            int slot = lp ^ ((lp >> 4) & 2);
            frag[kc_h][slot][jh] = (_Float16)h;
            if (t == TSTEPS - 1) hplain[m][u] = h;
        }
        // stage x_{t+1}
        if (t + 1 < TSTEPS && tid < 224) {
            int row = tid / 7, xg = tid % 7, xi = xg * 4;
            const float4* xs = (const float4*)(x + ((size_t)(b0 + row) * TSTEPS + (t + 1)) * IDIM);
            float4 xv = xs[xg];
            half4 hv = {(_Float16)xv.x, (_Float16)xv.y, (_Float16)xv.z, (_Float16)xv.w};
            int lp = row + 32 * ((xi >> 3) & 1);
            int slot = lp ^ ((lp >> 4) & 2);
            *((half4*)&frag[8 + (xi >> 4)][slot][xi & 7]) = hv;
        }
        __syncthreads();   // h/x writes visible before next step's GEMM
    }

    // ---- FC + ReLU epilogue ----
    for (int idx = tid; idx < TILE_B * CDIM; idx += 256) {
        int row = idx / CDIM, c = idx % CDIM;
        const float4* hv = (const float4*)&hplain[row][0];
        const float4* wf = (const float4*)(Wfc + c * HDIM);
        float s = b_fc[c];
        #pragma unroll
        for (int q = 0; q < 32; ++q) {
            float4 a = hv[q], b = wf[q];
            s += a.x * b.x + a.y * b.y + a.z * b.z + a.w * b.w;
        }
        out[(size_t)(b0 + row) * CDIM + c] = fmaxf(s, 0.f);
    }
}

extern "C" void kernel_launch(void* const* d_in, const int* in_sizes, int n_in,
                              void* d_out, int out_size, void* d_ws, size_t ws_size,
                              hipStream_t stream) {
    const float* x   = (const float*)d_in[0];
    const float* Wih = (const float*)d_in[1];
    const float* Whh = (const float*)d_in[2];
    const float* bih = (const float*)d_in[3];
    const float* bhh = (const float*)d_in[4];
    const float* Wfc = (const float*)d_in[5];
    const float* bfc = (const float*)d_in[6];
    float* out = (float*)d_out;
    _Float16* P = (_Float16*)d_ws;     // 160 KB packed weights

    hipLaunchKernelGGL(pack_w, dim3(320), dim3(256), 0, stream, Wih, Whh, P);
    hipLaunchKernelGGL(lstm_kernel, dim3(8192 / TILE_B), dim3(256), 0, stream,
                       x, P, bih, bhh, Wfc, bfc, out);
}

// Round 3
// 132.366 us; speedup vs baseline: 7.1854x; 1.1244x over previous
//
#include <hip/hip_runtime.h>
#include <math.h>

typedef __attribute__((ext_vector_type(8))) _Float16 half8;
typedef __attribute__((ext_vector_type(4))) _Float16 half4;
typedef __attribute__((ext_vector_type(4))) float    f32x4;

#define TSTEPS 28
#define IDIM   28
#define HDIM   128
#define NKC    5       // K chunks of 32: 160 = 128 (h) + 28 (x) + 4 (pad)
#define TILE_B 16
#define CDIM   10

#if __has_builtin(__builtin_amdgcn_exp2f)
#define EXP2F(x) __builtin_amdgcn_exp2f(x)
#else
#define EXP2F(x) exp2f(x)
#endif
#if __has_builtin(__builtin_amdgcn_rcpf)
#define RCPF(x) __builtin_amdgcn_rcpf(x)
#else
#define RCPF(x) (1.0f / (x))
#endif

// P[kc][t][w][lane][j] (f16): B-fragment order for mfma_f32_16x16x32_f16.
// Element = W_cat[k][col]: k = kc*32 + (lane>>4)*8 + j, col = t*128 + w*16 + (lane&15)
// (col -> gate type t, unit u = w*16 + (lane&15); PyTorch gate order i,f,g,o).
__global__ __launch_bounds__(256) void pack_w(const float* __restrict__ Wih,
                                              const float* __restrict__ Whh,
                                              _Float16* __restrict__ P) {
    int e = blockIdx.x * 256 + threadIdx.x;      // 5*4*8*64*8 = 81920
    if (e >= NKC * 4 * 8 * 64 * 8) return;
    int j  = e & 7;
    int ln = (e >> 3) & 63;
    int w  = (e >> 9) & 7;
    int t  = (e >> 12) & 3;
    int kc = e >> 14;
    int k  = kc * 32 + ((ln >> 4) << 3) + j;
    int u  = w * 16 + (ln & 15);
    int g  = t * HDIM + u;
    float v = 0.f;
    if (k < HDIM)              v = Whh[g * HDIM + k];
    else if (k < HDIM + IDIM)  v = Wih[g * IDIM + (k - HDIM)];
    P[e] = (_Float16)v;
}

__global__ __launch_bounds__(512, 4) void lstm_kernel(
    const float* __restrict__ x,          // [B][28][28] fp32
    const _Float16* __restrict__ P,       // packed weights, 160 KB
    const float* __restrict__ b_ih, const float* __restrict__ b_hh,
    const float* __restrict__ Wfc,        // [10][128]
    const float* __restrict__ b_fc,       // [10]
    float* __restrict__ out)              // [B][10]
{
    // A-fragments: frag[kc][slot][j]; slot = m + 16*quad == reading lane (identity)
    __shared__ __align__(16) _Float16 frag[NKC][64][8];        // 5 KB
    __shared__ __align__(16) _Float16 Plds[4][8][64][8];       // 32 KB (kc=4 B-frags)
    __shared__ __align__(16) float hplain[TILE_B][HDIM + 4];   // 8.25 KB

    const int tid = threadIdx.x;
    const int l   = tid & 63;
    const int w   = tid >> 6;                  // wave 0..7
    const int b0  = blockIdx.x * TILE_B;
    const int u   = w * 16 + (l & 15);         // this lane's unit

    // ---- stage B-frags for kc=4 into LDS (32 KB) ----
    {
        const float4* P4 = (const float4*)P;   // 8 f16 per float4
        float4* dst = (float4*)Plds;
        #pragma unroll
        for (int q = 0; q < 4; ++q)
            dst[tid + q * 512] = P4[8192 + tid + q * 512];
    }
    // ---- resident B-frags for kc=0..3 (64 VGPRs) ----
    half8 breg[4][4];
    {
        const half8* Pp = (const half8*)P;
        #pragma unroll
        for (int kc = 0; kc < 4; ++kc)
            #pragma unroll
            for (int t4 = 0; t4 < 4; ++t4)
                breg[t4][kc] = Pp[((kc * 4 + t4) * 8 + w) * 64 + l];
    }
    float biasv[4];
    #pragma unroll
    for (int t4 = 0; t4 < 4; ++t4)
        biasv[t4] = b_ih[t4 * HDIM + u] + b_hh[t4 * HDIM + u];

    // ---- zero h chunks frag[0..3] (8192 B = 512 float4) ----
    {
        float4 z = {0.f, 0.f, 0.f, 0.f};
        ((float4*)frag)[tid] = z;
        if (tid < 16) {                        // zero K-pad 156..159: quad 3, j 4..7
            half4 zh = {(_Float16)0.f, (_Float16)0.f, (_Float16)0.f, (_Float16)0.f};
            *(half4*)&frag[4][48 + tid][4] = zh;
        }
    }
    // ---- stage x_0 into frag[4] ----
    const int xrow = tid / 7, xg = tid % 7;
    if (tid < 112) {
        float4 xv = ((const float4*)(x + ((size_t)(b0 + xrow) * TSTEPS + 0) * IDIM))[xg];
        half4 hv = {(_Float16)xv.x, (_Float16)xv.y, (_Float16)xv.z, (_Float16)xv.w};
        *(half4*)&frag[4][xrow + 16 * (xg >> 1)][(xg & 1) * 4] = hv;
    }

    float cst[4] = {0.f, 0.f, 0.f, 0.f};
    const int kc_h = w >> 1;                       // u>>5 (wave-uniform)
    const int quad = (2 * w + ((l >> 3) & 1)) & 3; // (u>>3)&3
    const int jh   = l & 7;                        // u&7

    __syncthreads();

    for (int t = 0; t < TSTEPS; ++t) {
        // prefetch x_{t+1} early: latency hides behind the MFMA phase
        float4 xv;
        const bool doload = (t + 1 < TSTEPS) && (tid < 112);
        if (doload)
            xv = ((const float4*)(x + ((size_t)(b0 + xrow) * TSTEPS + (t + 1)) * IDIM))[xg];

        f32x4 acc[4];
        #pragma unroll
        for (int t4 = 0; t4 < 4; ++t4) {
            f32x4 a4 = {biasv[t4], biasv[t4], biasv[t4], biasv[t4]};
            acc[t4] = a4;
        }

        #pragma unroll
        for (int kc = 0; kc < NKC; ++kc) {
            half8 a = *(const half8*)&frag[kc][l][0];
            if (kc < 4) {
                acc[0] = __builtin_amdgcn_mfma_f32_16x16x32_f16(a, breg[0][kc], acc[0], 0, 0, 0);
                acc[1] = __builtin_amdgcn_mfma_f32_16x16x32_f16(a, breg[1][kc], acc[1], 0, 0, 0);
                acc[2] = __builtin_amdgcn_mfma_f32_16x16x32_f16(a, breg[2][kc], acc[2], 0, 0, 0);
                acc[3] = __builtin_amdgcn_mfma_f32_16x16x32_f16(a, breg[3][kc], acc[3], 0, 0, 0);
            } else {
                #pragma unroll
                for (int t4 = 0; t4 < 4; ++t4) {
                    half8 b = *(const half8*)&Plds[t4][w][l][0];
                    acc[t4] = __builtin_amdgcn_mfma_f32_16x16x32_f16(a, b, acc[t4], 0, 0, 0);
                }
            }
        }
        __syncthreads();   // all waves done reading frag before h/x overwrite

        #pragma unroll
        for (int r = 0; r < 4; ++r) {
            int m = ((l >> 4) << 2) + r;
            float ig = acc[0][r], fg = acc[1][r], gg = acc[2][r], og = acc[3][r];
            float is = RCPF(1.f + EXP2F(ig * -1.44269504f));
            float fs = RCPF(1.f + EXP2F(fg * -1.44269504f));
            float os = RCPF(1.f + EXP2F(og * -1.44269504f));
            float gt = 1.f - 2.f * RCPF(1.f + EXP2F(gg * 2.88539008f));
            float c  = fs * cst[r] + is * gt;
            cst[r] = c;
            float tc = 1.f - 2.f * RCPF(1.f + EXP2F(c * 2.88539008f));
            float h  = os * tc;
            frag[kc_h][m + 16 * quad][jh] = (_Float16)h;
            if (t == TSTEPS - 1) hplain[m][u] = h;
        }
        if (doload) {
            half4 hv = {(_Float16)xv.x, (_Float16)xv.y, (_Float16)xv.z, (_Float16)xv.w};
            *(half4*)&frag[4][xrow + 16 * (xg >> 1)][(xg & 1) * 4] = hv;
        }
        __syncthreads();   // h/x visible before next step's MFMA reads
    }

    // ---- FC + ReLU epilogue ----
    if (tid < TILE_B * CDIM) {
        int row = tid / CDIM, c = tid % CDIM;
        const float4* hv = (const float4*)&hplain[row][0];
        const float4* wf = (const float4*)(Wfc + c * HDIM);
        float s = b_fc[c];
        #pragma unroll
        for (int q = 0; q < 32; ++q) {
            float4 a = hv[q], b = wf[q];
            s += a.x * b.x + a.y * b.y + a.z * b.z + a.w * b.w;
        }
        out[(size_t)(b0 + row) * CDIM + c] = fmaxf(s, 0.f);
    }
}

extern "C" void kernel_launch(void* const* d_in, const int* in_sizes, int n_in,
                              void* d_out, int out_size, void* d_ws, size_t ws_size,
                              hipStream_t stream) {
    const float* x   = (const float*)d_in[0];
    const float* Wih = (const float*)d_in[1];
    const float* Whh = (const float*)d_in[2];
    const float* bih = (const float*)d_in[3];
    const float* bhh = (const float*)d_in[4];
    const float* Wfc = (const float*)d_in[5];
    const float* bfc = (const float*)d_in[6];
    float* out = (float*)d_out;
    _Float16* P = (_Float16*)d_ws;     // 160 KB packed weights

    hipLaunchKernelGGL(pack_w, dim3(320), dim3(256), 0, stream, Wih, Whh, P);
    hipLaunchKernelGGL(lstm_kernel, dim3(8192 / TILE_B), dim3(512), 0, stream,
                       x, P, bih, bhh, Wfc, bfc, out);
}

// Round 4
// 127.496 us; speedup vs baseline: 7.4598x; 1.0382x over previous
//
#include <hip/hip_runtime.h>
#include <math.h>

typedef __attribute__((ext_vector_type(8))) _Float16 half8;
typedef __attribute__((ext_vector_type(4))) _Float16 half4;
typedef __attribute__((ext_vector_type(4))) float    f32x4;

#define TSTEPS 28
#define IDIM   28
#define HDIM   128
#define NKC    5       // K chunks of 32: 160 = 128 (h) + 28 (x) + 4 (pad)
#define TILE_B 16
#define CDIM   10

#if __has_builtin(__builtin_amdgcn_exp2f)
#define EXP2F(x) __builtin_amdgcn_exp2f(x)
#else
#define EXP2F(x) exp2f(x)
#endif
#if __has_builtin(__builtin_amdgcn_rcpf)
#define RCPF(x) __builtin_amdgcn_rcpf(x)
#else
#define RCPF(x) (1.0f / (x))
#endif

#define NLOG2E (-1.44269504f)
#define P2LOG2E (2.88539008f)

// P[kc][t][w][lane][j] (f16): B-fragment order for mfma_f32_16x16x32_f16,
// with per-gate activation scale folded in: i,f,o cols x -log2e; g cols x 2*log2e.
// Element = W_cat[k][col]*sc: k = kc*32 + (lane>>4)*8 + j, col = t*128 + w*16 + (lane&15)
__global__ __launch_bounds__(256) void pack_w(const float* __restrict__ Wih,
                                              const float* __restrict__ Whh,
                                              _Float16* __restrict__ P) {
    int e = blockIdx.x * 256 + threadIdx.x;      // 5*4*8*64*8 = 81920
    if (e >= NKC * 4 * 8 * 64 * 8) return;
    int j  = e & 7;
    int ln = (e >> 3) & 63;
    int w  = (e >> 9) & 7;
    int t  = (e >> 12) & 3;
    int kc = e >> 14;
    int k  = kc * 32 + ((ln >> 4) << 3) + j;
    int u  = w * 16 + (ln & 15);
    int g  = t * HDIM + u;
    float v = 0.f;
    if (k < HDIM)              v = Whh[g * HDIM + k];
    else if (k < HDIM + IDIM)  v = Wih[g * IDIM + (k - HDIM)];
    float sc = (t == 2) ? P2LOG2E : NLOG2E;
    P[e] = (_Float16)(v * sc);
}

__global__ __launch_bounds__(512, 4) void lstm_kernel(
    const float* __restrict__ x,          // [B][28][28] fp32
    const _Float16* __restrict__ P,       // packed weights, 160 KB
    const float* __restrict__ b_ih, const float* __restrict__ b_hh,
    const float* __restrict__ Wfc,        // [10][128]
    const float* __restrict__ b_fc,       // [10]
    float* __restrict__ out)              // [B][10]
{
    // Double-buffered A-fragments: frag[buf][kc][slot][j]; slot == reading lane
    __shared__ __align__(16) _Float16 frag[2][NKC][64][8];     // 10 KB
    __shared__ __align__(16) _Float16 Plds[4][8][64][8];       // 32 KB (kc=4 B-frags)
    __shared__ __align__(16) float hplain[TILE_B][HDIM + 4];   // 8.25 KB

    const int tid = threadIdx.x;
    const int l   = tid & 63;
    const int w   = tid >> 6;                  // wave 0..7
    const int b0  = blockIdx.x * TILE_B;
    const int u   = w * 16 + (l & 15);         // this lane's unit

    // ---- stage B-frags for kc=4 into LDS (32 KB) ----
    {
        const float4* P4 = (const float4*)P;   // 8 f16 per float4
        float4* dst = (float4*)Plds;
        #pragma unroll
        for (int q = 0; q < 4; ++q)
            dst[tid + q * 512] = P4[8192 + tid + q * 512];
    }
    // ---- resident B-frags for kc=0..3 (compiler parks these in AGPRs) ----
    half8 breg[4][4];
    {
        const half8* Pp = (const half8*)P;
        #pragma unroll
        for (int kc = 0; kc < 4; ++kc)
            #pragma unroll
            for (int t4 = 0; t4 < 4; ++t4)
                breg[t4][kc] = Pp[((kc * 4 + t4) * 8 + w) * 64 + l];
    }
    float biasv[4];
    #pragma unroll
    for (int t4 = 0; t4 < 4; ++t4) {
        float sc = (t4 == 2) ? P2LOG2E : NLOG2E;
        biasv[t4] = (b_ih[t4 * HDIM + u] + b_hh[t4 * HDIM + u]) * sc;
    }

    // ---- zero h chunks of buf0 (chunks 0..3 = 4096 B = 256 float4) ----
    {
        float4 z = {0.f, 0.f, 0.f, 0.f};
        if (tid < 256) ((float4*)&frag[0][0][0][0])[tid] = z;
        if (tid < 32) {                        // zero K-pad 156..159 in BOTH buffers
            int b = tid >> 4, i = tid & 15;
            half4 zh = {(_Float16)0.f, (_Float16)0.f, (_Float16)0.f, (_Float16)0.f};
            *(half4*)&frag[b][4][48 + i][4] = zh;
        }
    }
    // ---- stage x_0 into buf0 chunk 4 ----
    const int xrow = tid / 7, xg = tid % 7;
    if (tid < 112) {
        float4 xv = ((const float4*)(x + ((size_t)(b0 + xrow) * TSTEPS + 0) * IDIM))[xg];
        half4 hv = {(_Float16)xv.x, (_Float16)xv.y, (_Float16)xv.z, (_Float16)xv.w};
        *(half4*)&frag[0][4][xrow + 16 * (xg >> 1)][(xg & 1) * 4] = hv;
    }

    float cst[4] = {0.f, 0.f, 0.f, 0.f};
    const int kc_h = w >> 1;                       // u>>5 (wave-uniform)
    const int quad = (2 * w + ((l >> 3) & 1)) & 3; // (u>>3)&3
    const int jh   = l & 7;                        // u&7

    __syncthreads();

    // one step: read A-frags from `cur`, write h/x_{t+1} into `nxt`, ONE barrier
    auto step = [&](int t, _Float16 (*cur)[64][8], _Float16 (*nxt)[64][8]) {
        float4 xv;
        const bool doload = (t + 1 < TSTEPS) && (tid < 112);
        if (doload)
            xv = ((const float4*)(x + ((size_t)(b0 + xrow) * TSTEPS + (t + 1)) * IDIM))[xg];

        f32x4 acc[4];
        #pragma unroll
        for (int t4 = 0; t4 < 4; ++t4) {
            f32x4 a4 = {biasv[t4], biasv[t4], biasv[t4], biasv[t4]};
            acc[t4] = a4;
        }

        #pragma unroll
        for (int kc = 0; kc < NKC; ++kc) {
            half8 a = *(const half8*)&cur[kc][l][0];
            if (kc < 4) {
                acc[0] = __builtin_amdgcn_mfma_f32_16x16x32_f16(a, breg[0][kc], acc[0], 0, 0, 0);
                acc[1] = __builtin_amdgcn_mfma_f32_16x16x32_f16(a, breg[1][kc], acc[1], 0, 0, 0);
                acc[2] = __builtin_amdgcn_mfma_f32_16x16x32_f16(a, breg[2][kc], acc[2], 0, 0, 0);
                acc[3] = __builtin_amdgcn_mfma_f32_16x16x32_f16(a, breg[3][kc], acc[3], 0, 0, 0);
            } else {
                #pragma unroll
                for (int t4 = 0; t4 < 4; ++t4) {
                    half8 b = *(const half8*)&Plds[t4][w][l][0];
                    acc[t4] = __builtin_amdgcn_mfma_f32_16x16x32_f16(a, b, acc[t4], 0, 0, 0);
                }
            }
        }

        // activations (scales pre-folded: i,f,o gates hold -x*log2e; g holds 2x*log2e)
        #pragma unroll
        for (int r = 0; r < 4; ++r) {
            int m = ((l >> 4) << 2) + r;
            float is = RCPF(1.f + EXP2F(acc[0][r]));
            float fs = RCPF(1.f + EXP2F(acc[1][r]));
            float os = RCPF(1.f + EXP2F(acc[3][r]));
            float gt = 1.f - 2.f * RCPF(1.f + EXP2F(acc[2][r]));
            float c  = fs * cst[r] + is * gt;
            cst[r] = c;
            float tc = 1.f - 2.f * RCPF(1.f + EXP2F(c * P2LOG2E));
            float h  = os * tc;
            nxt[kc_h][m + 16 * quad][jh] = (_Float16)h;
            if (t == TSTEPS - 1) hplain[m][u] = h;
        }
        if (doload) {
            half4 hv = {(_Float16)xv.x, (_Float16)xv.y, (_Float16)xv.z, (_Float16)xv.w};
            *(half4*)&nxt[4][xrow + 16 * (xg >> 1)][(xg & 1) * 4] = hv;
        }
        __syncthreads();   // writes to nxt visible; all reads of cur already done
    };

    for (int tt = 0; tt < TSTEPS; tt += 2) {
        step(tt,     frag[0], frag[1]);
        step(tt + 1, frag[1], frag[0]);
    }

    // ---- FC + ReLU epilogue ----
    if (tid < TILE_B * CDIM) {
        int row = tid / CDIM, c = tid % CDIM;
        const float4* hv = (const float4*)&hplain[row][0];
        const float4* wf = (const float4*)(Wfc + c * HDIM);
        float s = b_fc[c];
        #pragma unroll
        for (int q = 0; q < 32; ++q) {
            float4 a = hv[q], b = wf[q];
            s += a.x * b.x + a.y * b.y + a.z * b.z + a.w * b.w;
        }
        out[(size_t)(b0 + row) * CDIM + c] = fmaxf(s, 0.f);
    }
}

extern "C" void kernel_launch(void* const* d_in, const int* in_sizes, int n_in,
                              void* d_out, int out_size, void* d_ws, size_t ws_size,
                              hipStream_t stream) {
    const float* x   = (const float*)d_in[0];
    const float* Wih = (const float*)d_in[1];
    const float* Whh = (const float*)d_in[2];
    const float* bih = (const float*)d_in[3];
    const float* bhh = (const float*)d_in[4];
    const float* Wfc = (const float*)d_in[5];
    const float* bfc = (const float*)d_in[6];
    float* out = (float*)d_out;
    _Float16* P = (_Float16*)d_ws;     // 160 KB packed weights

    hipLaunchKernelGGL(pack_w, dim3(320), dim3(256), 0, stream, Wih, Whh, P);
    hipLaunchKernelGGL(lstm_kernel, dim3(8192 / TILE_B), dim3(512), 0, stream,
                       x, P, bih, bhh, Wfc, bfc, out);
}

// Round 5
// 127.208 us; speedup vs baseline: 7.4767x; 1.0023x over previous
//
#include <hip/hip_runtime.h>
#include <math.h>

typedef __attribute__((ext_vector_type(8))) _Float16 half8;
typedef __attribute__((ext_vector_type(4))) _Float16 half4;
typedef __attribute__((ext_vector_type(4))) float    f32x4;

#define TSTEPS 28
#define IDIM   28
#define HDIM   128
#define NKC    5       // K chunks of 32: 160 = 128 (h) + 28 (x) + 4 (pad)
#define CDIM   10

#if __has_builtin(__builtin_amdgcn_exp2f)
#define EXP2F(x) __builtin_amdgcn_exp2f(x)
#else
#define EXP2F(x) exp2f(x)
#endif
#if __has_builtin(__builtin_amdgcn_rcpf)
#define RCPF(x) __builtin_amdgcn_rcpf(x)
#else
#define RCPF(x) (1.0f / (x))
#endif

#define NLOG2E (-1.44269504f)
#define P2LOG2E (2.88539008f)

// P[kc][t][w][lane][j] (f16): B-fragment order for mfma_f32_16x16x32_f16,
// with activation scales folded: i,f,o cols x -log2e; g cols x 2*log2e.
__global__ __launch_bounds__(256) void pack_w(const float* __restrict__ Wih,
                                              const float* __restrict__ Whh,
                                              _Float16* __restrict__ P) {
    int e = blockIdx.x * 256 + threadIdx.x;      // 5*4*8*64*8 = 81920
    if (e >= NKC * 4 * 8 * 64 * 8) return;
    int j  = e & 7;
    int ln = (e >> 3) & 63;
    int w  = (e >> 9) & 7;
    int t  = (e >> 12) & 3;
    int kc = e >> 14;
    int k  = kc * 32 + ((ln >> 4) << 3) + j;
    int u  = w * 16 + (ln & 15);
    int g  = t * HDIM + u;
    float v = 0.f;
    if (k < HDIM)              v = Whh[g * HDIM + k];
    else if (k < HDIM + IDIM)  v = Wih[g * IDIM + (k - HDIM)];
    float sc = (t == 2) ? P2LOG2E : NLOG2E;
    P[e] = (_Float16)(v * sc);
}

__global__ __launch_bounds__(512, 2) void lstm_kernel(
    const float* __restrict__ x,          // [B][28][28] fp32
    const _Float16* __restrict__ P,       // packed weights, 160 KB
    const float* __restrict__ b_ih, const float* __restrict__ b_hh,
    const float* __restrict__ Wfc,        // [10][128]
    const float* __restrict__ b_fc,       // [10]
    float* __restrict__ out)              // [B][10]
{
    // A-fragments: frag[tile][buf][kc][slot][j]; slot == reading lane
    __shared__ __align__(16) _Float16 frag[2][2][NKC][64][8];  // 20 KB
    __shared__ __align__(16) _Float16 Plds[4][8][64][8];       // 32 KB (kc=4 B-frags)
    __shared__ __align__(16) float hplain[32][HDIM + 4];       // 16.5 KB

    const int tid = threadIdx.x;
    const int l   = tid & 63;
    const int w   = tid >> 6;                  // wave 0..7
    const int b0  = blockIdx.x * 32;
    const int u   = w * 16 + (l & 15);         // this lane's unit

    // ---- stage B-frags for kc=4 into LDS ----
    {
        const float4* P4 = (const float4*)P;
        float4* dst = (float4*)Plds;
        #pragma unroll
        for (int q = 0; q < 4; ++q)
            dst[tid + q * 512] = P4[8192 + tid + q * 512];
    }
    // ---- resident B-frags for kc=0..3 (parked in AGPRs) ----
    half8 breg[4][4];
    {
        const half8* Pp = (const half8*)P;
        #pragma unroll
        for (int kc = 0; kc < 4; ++kc)
            #pragma unroll
            for (int t4 = 0; t4 < 4; ++t4)
                breg[t4][kc] = Pp[((kc * 4 + t4) * 8 + w) * 64 + l];
    }
    float biasv[4];
    #pragma unroll
    for (int t4 = 0; t4 < 4; ++t4) {
        float sc = (t4 == 2) ? P2LOG2E : NLOG2E;
        biasv[t4] = (b_ih[t4 * HDIM + u] + b_hh[t4 * HDIM + u]) * sc;
    }

    // ---- zero h chunks of buf0 (both tiles) + K-pad (all tile/buf) ----
    {
        float4 z = {0.f, 0.f, 0.f, 0.f};
        int tile = tid >> 8, q = tid & 255;    // 256 float4 = chunks 0..3 of one buf
        ((float4*)&frag[tile][0][0][0][0])[q] = z;
        if (tid < 64) {
            int tb = tid >> 4, i = tid & 15;
            half4 zh = {(_Float16)0.f, (_Float16)0.f, (_Float16)0.f, (_Float16)0.f};
            *(half4*)&frag[tb >> 1][tb & 1][4][48 + i][4] = zh;
        }
    }
    // ---- stage x_0 into buf0 chunk 4; prefetch x_1 into regs ----
    const int xrow = tid / 7, xg = tid % 7;    // row 0..31, float4 group 0..6
    float4 xheld;
    if (tid < 224) {
        float4 xv = ((const float4*)(x + ((size_t)(b0 + xrow) * TSTEPS + 0) * IDIM))[xg];
        half4 hv = {(_Float16)xv.x, (_Float16)xv.y, (_Float16)xv.z, (_Float16)xv.w};
        *(half4*)&frag[xrow >> 4][0][4][(xrow & 15) + 16 * (xg >> 1)][(xg & 1) * 4] = hv;
        xheld = ((const float4*)(x + ((size_t)(b0 + xrow) * TSTEPS + 1) * IDIM))[xg];
    }

    float cst0[4] = {0.f, 0.f, 0.f, 0.f};
    float cst1[4] = {0.f, 0.f, 0.f, 0.f};
    const int kc_h = w >> 1;                       // u>>5 (wave-uniform)
    const int quad = (2 * w + ((l >> 3) & 1)) & 3; // (u>>3)&3
    const int jh   = l & 7;                        // u&7

    f32x4 acc0[4], acc1[4];

    auto mfma_kc = [&](f32x4 (&acc)[4], const _Float16 (*cur)[64][8], int kc) {
        half8 a = *(const half8*)&cur[kc][l][0];
        if (kc < 4) {
            acc[0] = __builtin_amdgcn_mfma_f32_16x16x32_f16(a, breg[0][kc], acc[0], 0, 0, 0);
            acc[1] = __builtin_amdgcn_mfma_f32_16x16x32_f16(a, breg[1][kc], acc[1], 0, 0, 0);
            acc[2] = __builtin_amdgcn_mfma_f32_16x16x32_f16(a, breg[2][kc], acc[2], 0, 0, 0);
            acc[3] = __builtin_amdgcn_mfma_f32_16x16x32_f16(a, breg[3][kc], acc[3], 0, 0, 0);
        } else {
            #pragma unroll
            for (int t4 = 0; t4 < 4; ++t4) {
                half8 b = *(const half8*)&Plds[t4][w][l][0];
                acc[t4] = __builtin_amdgcn_mfma_f32_16x16x32_f16(a, b, acc[t4], 0, 0, 0);
            }
        }
    };
    auto init_acc = [&](f32x4 (&acc)[4]) {
        #pragma unroll
        for (int t4 = 0; t4 < 4; ++t4) {
            f32x4 a4 = {biasv[t4], biasv[t4], biasv[t4], biasv[t4]};
            acc[t4] = a4;
        }
    };
    // activation for one cell r of one tile; rcp-paired (8 trans instead of 10)
    auto act_cell = [&](f32x4 (&acc)[4], float (&cst)[4], int tile, int r,
                        bool last, int nb) {
        float Ei = EXP2F(acc[0][r]);     // e^{-i}
        float Ef = EXP2F(acc[1][r]);     // e^{-f}
        float Eg = EXP2F(acc[2][r]);     // e^{2g}
        float Eo = EXP2F(acc[3][r]);     // e^{-o}
        float Di = 1.f + Ei, Df = 1.f + Ef, Dg = 1.f + Eg, Do = 1.f + Eo;
        float Rif = RCPF(Di * Df);
        float Rgo = RCPF(Dg * Do);
        float is = Rif * Df, fs = Rif * Di;
        float gt = 1.f - 2.f * (Rgo * Do);
        float os = Rgo * Dg;
        float c  = fs * cst[r] + is * gt;
        cst[r] = c;
        float tc = 1.f - 2.f * RCPF(1.f + EXP2F(c * P2LOG2E));
        float h  = os * tc;
        int m = ((l >> 4) << 2) + r;
        frag[tile][nb][kc_h][m + 16 * quad][jh] = (_Float16)h;
        if (last) hplain[tile * 16 + m][u] = h;
    };

    __syncthreads();

    // warm-up: MFMA(T0, t=0)
    init_acc(acc0);
    mfma_kc(acc0, frag[0][0], 0);
    mfma_kc(acc0, frag[0][0], 1);
    mfma_kc(acc0, frag[0][0], 2);
    mfma_kc(acc0, frag[0][0], 3);
    mfma_kc(acc0, frag[0][0], 4);

    for (int t = 0; t < TSTEPS; ++t) {
        const int cb = t & 1, nb = cb ^ 1;
        const bool last = (t == TSTEPS - 1);

        // ===== phase A: MFMA(T1,t) interleaved with act(T0,t) =====
        if (t + 1 < TSTEPS && tid < 224) {     // commit x_{t+1} (loaded 2 phases ago)
            half4 hv = {(_Float16)xheld.x, (_Float16)xheld.y,
                        (_Float16)xheld.z, (_Float16)xheld.w};
            *(half4*)&frag[xrow >> 4][nb][4][(xrow & 15) + 16 * (xg >> 1)][(xg & 1) * 4] = hv;
        }
        if (t + 2 < TSTEPS && tid < 224)       // prefetch x_{t+2}
            xheld = ((const float4*)(x + ((size_t)(b0 + xrow) * TSTEPS + (t + 2)) * IDIM))[xg];

        init_acc(acc1);
        mfma_kc(acc1, frag[1][cb], 0);
        act_cell(acc0, cst0, 0, 0, last, nb);
        mfma_kc(acc1, frag[1][cb], 1);
        act_cell(acc0, cst0, 0, 1, last, nb);
        mfma_kc(acc1, frag[1][cb], 2);
        act_cell(acc0, cst0, 0, 2, last, nb);
        mfma_kc(acc1, frag[1][cb], 3);
        act_cell(acc0, cst0, 0, 3, last, nb);
        mfma_kc(acc1, frag[1][cb], 4);
        __syncthreads();

        // ===== phase B: MFMA(T0,t+1) interleaved with act(T1,t) =====
        if (!last) {
            init_acc(acc0);
            mfma_kc(acc0, frag[0][nb], 0);
            act_cell(acc1, cst1, 1, 0, last, nb);
            mfma_kc(acc0, frag[0][nb], 1);
            act_cell(acc1, cst1, 1, 1, last, nb);
            mfma_kc(acc0, frag[0][nb], 2);
            act_cell(acc1, cst1, 1, 2, last, nb);
            mfma_kc(acc0, frag[0][nb], 3);
            act_cell(acc1, cst1, 1, 3, last, nb);
            mfma_kc(acc0, frag[0][nb], 4);
        } else {
            act_cell(acc1, cst1, 1, 0, last, nb);
            act_cell(acc1, cst1, 1, 1, last, nb);
            act_cell(acc1, cst1, 1, 2, last, nb);
            act_cell(acc1, cst1, 1, 3, last, nb);
        }
        __syncthreads();
    }

    // ---- FC + ReLU epilogue: 32 rows x 10 classes ----
    if (tid < 32 * CDIM) {
        int row = tid / CDIM, c = tid % CDIM;
        const float4* hv = (const float4*)&hplain[row][0];
        const float4* wf = (const float4*)(Wfc + c * HDIM);
        float s = b_fc[c];
        #pragma unroll
        for (int q = 0; q < 32; ++q) {
            float4 a = hv[q], b = wf[q];
            s += a.x * b.x + a.y * b.y + a.z * b.z + a.w * b.w;
        }
        out[(size_t)(b0 + row) * CDIM + c] = fmaxf(s, 0.f);
    }
}

extern "C" void kernel_launch(void* const* d_in, const int* in_sizes, int n_in,
                              void* d_out, int out_size, void* d_ws, size_t ws_size,
                              hipStream_t stream) {
    const float* x   = (const float*)d_in[0];
    const float* Wih = (const float*)d_in[1];
    const float* Whh = (const float*)d_in[2];
    const float* bih = (const float*)d_in[3];
    const float* bhh = (const float*)d_in[4];
    const float* Wfc = (const float*)d_in[5];
    const float* bfc = (const float*)d_in[6];
    float* out = (float*)d_out;
    _Float16* P = (_Float16*)d_ws;     // 160 KB packed weights

    hipLaunchKernelGGL(pack_w, dim3(320), dim3(256), 0, stream, Wih, Whh, P);
    hipLaunchKernelGGL(lstm_kernel, dim3(8192 / 32), dim3(512), 0, stream,
                       x, P, bih, bhh, Wfc, bfc, out);
}